// Round 1
// baseline (220.033 us; speedup 1.0000x reference)
//
#include <hip/hip_runtime.h>

#define NP 320                  // particles
#define HD 32                   // hidden dim
#define MT 4                    // trajectories
#define LS 6                    // snapshots
#define BB (MT * (LS - 1))      // 20 batch elements
#define SIG2 0.01f              // sigma^2

__device__ __forceinline__ float fast_tanh(float x) {
    float e = __expf(2.0f * x);
    return 1.0f - 2.0f / (e + 1.0f);
}

// --------------------------------------------------------------------------
// Kernel A: pairwise pass over X_curr. One block per (b, i) row.
// Accumulates dt*(|drift_i|^2/N) + sig2*dt*lap_sum_i/N into acc[0].
// --------------------------------------------------------------------------
__global__ __launch_bounds__(NP) void pair_curr_kernel(
    const float* __restrict__ data,      // (MT, LS, NP, 2)
    const float* __restrict__ t_snap,    // (LS,)
    const float* __restrict__ V_w1,      // (2, HD)
    const float* __restrict__ V_b1,      // (HD,)
    const float* __restrict__ V_w2,      // (HD,)
    const float* __restrict__ Phi_w1,    // (HD,)
    const float* __restrict__ Phi_b1,    // (HD,)
    const float* __restrict__ Phi_w2,    // (HD,)
    float* __restrict__ acc)
{
    __shared__ float sW[HD], sB[HD], sC1[HD], sC2[HD];
    __shared__ float sRed[NP / 64][3];

    const int tid = threadIdx.x;
    const int row = blockIdx.x;          // b*NP + i
    const int b   = row / NP;
    const int i   = row - b * NP;
    const int m   = b / (LS - 1);
    const int l   = b - m * (LS - 1);
    const float* X = data + ((size_t)m * LS + l) * NP * 2;

    if (tid < HD) {
        float w  = Phi_w1[tid];
        float w2 = Phi_w2[tid];
        sW[tid]  = w;
        sB[tid]  = Phi_b1[tid];
        sC1[tid] = w * w2;           // for Phi'
        sC2[tid] = w * w * w2;       // for Phi''
    }
    __syncthreads();

    const float xi0 = X[2 * i];
    const float xi1 = X[2 * i + 1];

    const int j = tid;
    const float xj0 = X[2 * j];
    const float xj1 = X[2 * j + 1];
    const float d0 = xi0 - xj0;
    const float d1 = xi1 - xj1;
    const float sq = d0 * d0 + d1 * d1;
    const float dist = sqrtf(sq);
    const float dist_safe = fmaxf(dist, 1e-10f);

    float dphi = 0.0f, d2phi = 0.0f;
    #pragma unroll
    for (int h = 0; h < HD; ++h) {
        float t = fast_tanh(fmaf(dist, sW[h], sB[h]));
        float u = 1.0f - t * t;
        dphi  = fmaf(u, sC1[h], dphi);          // Phi'(r)
        d2phi = fmaf(t * u, sC2[h], d2phi);     // accumulate t*u*w^2*w2
    }
    d2phi *= -2.0f;                             // Phi''(r)

    const float inv = 1.0f / dist_safe;
    float gx = dphi * d0 * inv;                 // dPhi * unit_diff
    float gy = dphi * d1 * inv;
    float lp = d2phi + dphi * inv;              // lap_Phi (d=2 -> (d-1)=1)
    if (j == i) { gx = 0.0f; gy = 0.0f; lp = 0.0f; }

    // block reduction over 320 threads (5 waves)
    #pragma unroll
    for (int off = 32; off; off >>= 1) {
        gx += __shfl_down(gx, off, 64);
        gy += __shfl_down(gy, off, 64);
        lp += __shfl_down(lp, off, 64);
    }
    const int lane = tid & 63, wid = tid >> 6;
    if (lane == 0) { sRed[wid][0] = gx; sRed[wid][1] = gy; sRed[wid][2] = lp; }
    __syncthreads();

    if (tid == 0) {
        float GX = 0.0f, GY = 0.0f, LP = 0.0f;
        #pragma unroll
        for (int w = 0; w < NP / 64; ++w) {
            GX += sRed[w][0]; GY += sRed[w][1]; LP += sRed[w][2];
        }
        // one-body terms: grad V and lap V at x_i (closed-form)
        float gvx = 0.0f, gvy = 0.0f, lv = 0.0f;
        #pragma unroll
        for (int h = 0; h < HD; ++h) {
            float w0 = V_w1[h];
            float w1 = V_w1[HD + h];
            float z  = fmaf(xi0, w0, fmaf(xi1, w1, V_b1[h]));
            float t  = fast_tanh(z);
            float u  = 1.0f - t * t;
            float v2 = V_w2[h];
            gvx = fmaf(u * w0, v2, gvx);
            gvy = fmaf(u * w1, v2, gvy);
            lv  = fmaf(-2.0f * t * u * (w0 * w0 + w1 * w1), v2, lv);
        }
        const float invN = 1.0f / (float)NP;
        float dx = -gvx - GX * invN;
        float dy = -gvy - GY * invN;
        float lap_sum = lv + LP * invN;
        float dt = t_snap[l + 1] - t_snap[l];
        float contrib = dt * (dx * dx + dy * dy) * invN
                      + SIG2 * dt * lap_sum * invN;
        atomicAdd(acc, contrib);
    }
}

// --------------------------------------------------------------------------
// Kernel B: energy of the 2*MT boundary configs (telescoped J_energy).
// config c: m = c>>1, l = (c&1) ? LS-1 : 0, coefficient -1 for l=0, +1 for l=LS-1.
// Accumulates coef * E into acc[1].
// --------------------------------------------------------------------------
__global__ __launch_bounds__(NP) void energy_kernel(
    const float* __restrict__ data,
    const float* __restrict__ V_w1, const float* __restrict__ V_b1,
    const float* __restrict__ V_w2, const float* __restrict__ V_b2,
    const float* __restrict__ Phi_w1, const float* __restrict__ Phi_b1,
    const float* __restrict__ Phi_w2, const float* __restrict__ Phi_b2,
    float* __restrict__ acc)
{
    __shared__ float sW[HD], sB[HD], sW2[HD];
    __shared__ float sRed[NP / 64];

    const int tid = threadIdx.x;
    const int row = blockIdx.x;           // c*NP + i
    const int c   = row / NP;
    const int i   = row - c * NP;
    const int m   = c >> 1;
    const int l   = (c & 1) ? (LS - 1) : 0;
    const float coef = (c & 1) ? 1.0f : -1.0f;
    const float* X = data + ((size_t)m * LS + l) * NP * 2;

    if (tid < HD) {
        sW[tid]  = Phi_w1[tid];
        sB[tid]  = Phi_b1[tid];
        sW2[tid] = Phi_w2[tid];
    }
    __syncthreads();

    const float xi0 = X[2 * i];
    const float xi1 = X[2 * i + 1];
    const int j = tid;
    const float d0 = xi0 - X[2 * j];
    const float d1 = xi1 - X[2 * j + 1];
    const float dist = sqrtf(d0 * d0 + d1 * d1);

    float phi = 0.0f;
    #pragma unroll
    for (int h = 0; h < HD; ++h) {
        float t = fast_tanh(fmaf(dist, sW[h], sB[h]));
        phi = fmaf(t, sW2[h], phi);
    }
    if (j == i) phi = 0.0f;               // diagonal mask (Phi_b2 added for off-diag below)

    #pragma unroll
    for (int off = 32; off; off >>= 1) phi += __shfl_down(phi, off, 64);
    const int lane = tid & 63, wid = tid >> 6;
    if (lane == 0) sRed[wid] = phi;
    __syncthreads();

    if (tid == 0) {
        float P = 0.0f;
        #pragma unroll
        for (int w = 0; w < NP / 64; ++w) P += sRed[w];
        P += (float)(NP - 1) * Phi_b2[0];  // Phi_b2 for each off-diagonal pair in this row
        // V(x_i)
        float v = V_b2[0];
        #pragma unroll
        for (int h = 0; h < HD; ++h) {
            float z = fmaf(xi0, V_w1[h], fmaf(xi1, V_w1[HD + h], V_b1[h]));
            v = fmaf(fast_tanh(z), V_w2[h], v);
        }
        const float invN = 1.0f / (float)NP;
        atomicAdd(acc + 1, coef * (v * invN + P * invN * invN));
    }
}

__global__ void finalize_kernel(const float* __restrict__ acc,
                                float* __restrict__ out)
{
    float res = (acc[0] - 2.0f * acc[1]) / (float)BB;
    out[0] = res * res;
}

extern "C" void kernel_launch(void* const* d_in, const int* in_sizes, int n_in,
                              void* d_out, int out_size, void* d_ws, size_t ws_size,
                              hipStream_t stream) {
    const float* data    = (const float*)d_in[0];
    const float* t_snap  = (const float*)d_in[1];
    const float* V_w1    = (const float*)d_in[2];
    const float* V_b1    = (const float*)d_in[3];
    const float* V_w2    = (const float*)d_in[4];
    const float* V_b2    = (const float*)d_in[5];
    const float* Phi_w1  = (const float*)d_in[6];
    const float* Phi_b1  = (const float*)d_in[7];
    const float* Phi_w2  = (const float*)d_in[8];
    const float* Phi_b2  = (const float*)d_in[9];
    float* acc = (float*)d_ws;
    float* out = (float*)d_out;

    hipMemsetAsync(acc, 0, 2 * sizeof(float), stream);

    pair_curr_kernel<<<BB * NP, NP, 0, stream>>>(
        data, t_snap, V_w1, V_b1, V_w2, Phi_w1, Phi_b1, Phi_w2, acc);

    energy_kernel<<<2 * MT * NP, NP, 0, stream>>>(
        data, V_w1, V_b1, V_w2, V_b2, Phi_w1, Phi_b1, Phi_w2, Phi_b2, acc);

    finalize_kernel<<<1, 1, 0, stream>>>(acc, out);
}

// Round 2
// 106.504 us; speedup vs baseline: 2.0660x; 2.0660x over previous
//
#include <hip/hip_runtime.h>

#define NP 320                  // particles
#define HD 32                   // hidden dim
#define MT 4                    // trajectories
#define LS 6                    // snapshots
#define BB (MT * (LS - 1))      // 20 batch elements
#define NEC (2 * MT)            // energy configs (telescoped boundaries)
#define SIG2 0.01f              // sigma^2
#define L2E2 2.8853900817779268f  // 2*log2(e)

#define PAIR_ROWS (BB * NP)     // 6400
#define EN_ROWS   (NEC * NP)    // 2560

__device__ __forceinline__ float fexp2(float x) { return __builtin_amdgcn_exp2f(x); }
__device__ __forceinline__ float frcp(float x)  { return __builtin_amdgcn_rcpf(x); }

// --------------------------------------------------------------------------
// Merged kernel: blocks [0, PAIR_ROWS) do the pairwise drift/laplacian pass
// over X_curr; blocks [PAIR_ROWS, PAIR_ROWS+EN_ROWS) do the telescoped
// boundary energies. Each block = one (config, i) row, 320 threads = one j
// each. Per-row partials are written to ws (no atomics).
//
// tanh(x) = 1 - 2r,  r = 1/(exp2(L2E2*x)+1)
//   1 - t^2   = 4(r - r^2)            = 4*u
//   t*(1-t^2) = 4(r - r^2)(1 - 2r)    = 4*tu
// --------------------------------------------------------------------------
__global__ __launch_bounds__(NP) void main_kernel(
    const float* __restrict__ data,      // (MT, LS, NP, 2)
    const float* __restrict__ t_snap,    // (LS,)
    const float* __restrict__ V_w1,      // (2, HD)
    const float* __restrict__ V_b1,      // (HD,)
    const float* __restrict__ V_w2,      // (HD,)
    const float* __restrict__ V_b2,      // (1,)
    const float* __restrict__ Phi_w1,    // (HD,)
    const float* __restrict__ Phi_b1,    // (HD,)
    const float* __restrict__ Phi_w2,    // (HD,)
    const float* __restrict__ Phi_b2,    // (1,)
    float* __restrict__ ws)              // [PAIR_ROWS] pair partials, then [EN_ROWS] energy partials
{
    __shared__ float4 sC[HD];
    __shared__ float sRed[NP / 64][3];

    const int tid  = threadIdx.x;
    const int lane = tid & 63, wid = tid >> 6;
    const int bid  = blockIdx.x;
    const bool is_pair = (bid < PAIR_ROWS);

    if (is_pair) {
        // ---------------- pairwise drift + laplacian pass ----------------
        const int row = bid;             // b*NP + i
        const int b   = row / NP;
        const int i   = row - b * NP;
        const int m   = b / (LS - 1);
        const int l   = b - m * (LS - 1);
        const float2* X = (const float2*)(data + ((size_t)m * LS + l) * NP * 2);

        if (tid < HD) {
            float w  = Phi_w1[tid];
            float bb = Phi_b1[tid];
            float w2 = Phi_w2[tid];
            sC[tid] = make_float4(w * L2E2, bb * L2E2,
                                  4.0f * w * w2, -8.0f * w * w * w2);
        }
        __syncthreads();

        const float2 xi = X[i];
        const float2 xj = X[tid];
        const float d0 = xi.x - xj.x;
        const float d1 = xi.y - xj.y;
        const float sq = d0 * d0 + d1 * d1;
        const float dist = sqrtf(sq);
        const float inv = frcp(fmaxf(dist, 1e-10f));

        float dphi = 0.0f, d2phi = 0.0f;
        #pragma unroll
        for (int h = 0; h < HD; ++h) {
            float4 c = sC[h];
            float e = fexp2(fmaf(dist, c.x, c.y));
            float r = frcp(e + 1.0f);
            float u = fmaf(-r, r, r);            // r - r^2
            float p = u * r;
            float tu = fmaf(-2.0f, p, u);        // u*(1-2r)
            dphi  = fmaf(u,  c.z, dphi);         // Phi'(r)
            d2phi = fmaf(tu, c.w, d2phi);        // Phi''(r)
        }

        float gx = dphi * d0 * inv;
        float gy = dphi * d1 * inv;
        float lp = d2phi + dphi * inv;           // d=2 -> +(d-1)/r * Phi'
        if (tid == i) { gx = 0.0f; gy = 0.0f; lp = 0.0f; }

        #pragma unroll
        for (int off = 32; off; off >>= 1) {
            gx += __shfl_down(gx, off, 64);
            gy += __shfl_down(gy, off, 64);
            lp += __shfl_down(lp, off, 64);
        }
        if (lane == 0) { sRed[wid][0] = gx; sRed[wid][1] = gy; sRed[wid][2] = lp; }
        __syncthreads();

        // one-body grad V / lap V at x_i, parallel over h = lane (wave 0)
        float gvx = 0.0f, gvy = 0.0f, lv = 0.0f;
        if (tid < HD) {
            float w0 = V_w1[tid];
            float w1 = V_w1[HD + tid];
            float bb = V_b1[tid];
            float v2 = V_w2[tid];
            float z  = fmaf(xi.x, w0, fmaf(xi.y, w1, bb));
            float e  = fexp2(z * L2E2);
            float r  = frcp(e + 1.0f);
            float u  = fmaf(-r, r, r);
            float p  = u * r;
            float tu = fmaf(-2.0f, p, u);
            float u4 = 4.0f * u * v2;
            gvx = u4 * w0;
            gvy = u4 * w1;
            lv  = -8.0f * tu * v2 * (w0 * w0 + w1 * w1);
            #pragma unroll
            for (int off = 16; off; off >>= 1) {
                gvx += __shfl_xor(gvx, off, 64);
                gvy += __shfl_xor(gvy, off, 64);
                lv  += __shfl_xor(lv,  off, 64);
            }
        }

        if (tid == 0) {
            float GX = 0.0f, GY = 0.0f, LP = 0.0f;
            #pragma unroll
            for (int w = 0; w < NP / 64; ++w) {
                GX += sRed[w][0]; GY += sRed[w][1]; LP += sRed[w][2];
            }
            const float invN = 1.0f / (float)NP;
            float dx = -gvx - GX * invN;
            float dy = -gvy - GY * invN;
            float lap_sum = lv + LP * invN;
            float dt = t_snap[l + 1] - t_snap[l];
            ws[row] = dt * (dx * dx + dy * dy) * invN
                    + SIG2 * dt * lap_sum * invN;
        }
    } else {
        // ---------------- telescoped boundary energies ----------------
        const int erow = bid - PAIR_ROWS;     // c*NP + i
        const int c    = erow / NP;
        const int i    = erow - c * NP;
        const int m    = c >> 1;
        const int l    = (c & 1) ? (LS - 1) : 0;
        const float coef = (c & 1) ? 1.0f : -1.0f;
        const float2* X = (const float2*)(data + ((size_t)m * LS + l) * NP * 2);

        if (tid < HD) {
            float w  = Phi_w1[tid];
            float bb = Phi_b1[tid];
            float w2 = Phi_w2[tid];
            sC[tid] = make_float4(w * L2E2, bb * L2E2, w2, 0.0f);
        }
        __syncthreads();

        const float2 xi = X[i];
        const float2 xj = X[tid];
        const float d0 = xi.x - xj.x;
        const float d1 = xi.y - xj.y;
        const float dist = sqrtf(d0 * d0 + d1 * d1);

        // phi_ij = sumW2 + Phi_b2 - 2 * sum_h w2[h]*r_h
        float acc = 0.0f;
        #pragma unroll
        for (int h = 0; h < HD; ++h) {
            float4 c4 = sC[h];
            float e = fexp2(fmaf(dist, c4.x, c4.y));
            float r = frcp(e + 1.0f);
            acc = fmaf(c4.z, r, acc);
        }
        if (tid == i) acc = 0.0f;             // diagonal mask
        else          acc -= 0.0f;

        #pragma unroll
        for (int off = 32; off; off >>= 1) acc += __shfl_down(acc, off, 64);
        if (lane == 0) sRed[wid][0] = acc;
        __syncthreads();

        // V(x_i) = V_b2 + sumV2 - 2*sum_h v2[h]*r_h, parallel over h = lane
        float vr = 0.0f, v2s = 0.0f, w2s = 0.0f;
        if (tid < HD) {
            float w0 = V_w1[tid];
            float w1 = V_w1[HD + tid];
            float bb = V_b1[tid];
            float v2 = V_w2[tid];
            float z  = fmaf(xi.x, w0, fmaf(xi.y, w1, bb));
            float e  = fexp2(z * L2E2);
            float r  = frcp(e + 1.0f);
            vr  = v2 * r;
            v2s = v2;
            w2s = Phi_w2[tid];
            #pragma unroll
            for (int off = 16; off; off >>= 1) {
                vr  += __shfl_xor(vr,  off, 64);
                v2s += __shfl_xor(v2s, off, 64);
                w2s += __shfl_xor(w2s, off, 64);
            }
        }

        if (tid == 0) {
            float R = 0.0f;
            #pragma unroll
            for (int w = 0; w < NP / 64; ++w) R += sRed[w][0];
            const float invN = 1.0f / (float)NP;
            float v = V_b2[0] + v2s - 2.0f * vr;
            float P = (float)(NP - 1) * (w2s + Phi_b2[0]) - 2.0f * R;
            ws[PAIR_ROWS + erow] = coef * (v * invN + P * invN * invN);
        }
    }
}

// --------------------------------------------------------------------------
// Reduce: S0 = sum pair partials, S1 = sum energy partials (signs folded),
// out = ((S0 - 2*S1)/B)^2
// --------------------------------------------------------------------------
__global__ __launch_bounds__(1024) void reduce_kernel(
    const float* __restrict__ ws, float* __restrict__ out)
{
    __shared__ float sR[16][2];
    const int tid = threadIdx.x;
    float a0 = 0.0f, a1 = 0.0f;
    for (int idx = tid; idx < PAIR_ROWS; idx += 1024) a0 += ws[idx];
    for (int idx = tid; idx < EN_ROWS; idx += 1024)   a1 += ws[PAIR_ROWS + idx];
    #pragma unroll
    for (int off = 32; off; off >>= 1) {
        a0 += __shfl_down(a0, off, 64);
        a1 += __shfl_down(a1, off, 64);
    }
    const int lane = tid & 63, wid = tid >> 6;
    if (lane == 0) { sR[wid][0] = a0; sR[wid][1] = a1; }
    __syncthreads();
    if (tid == 0) {
        float S0 = 0.0f, S1 = 0.0f;
        #pragma unroll
        for (int w = 0; w < 16; ++w) { S0 += sR[w][0]; S1 += sR[w][1]; }
        float res = (S0 - 2.0f * S1) / (float)BB;
        out[0] = res * res;
    }
}

extern "C" void kernel_launch(void* const* d_in, const int* in_sizes, int n_in,
                              void* d_out, int out_size, void* d_ws, size_t ws_size,
                              hipStream_t stream) {
    const float* data    = (const float*)d_in[0];
    const float* t_snap  = (const float*)d_in[1];
    const float* V_w1    = (const float*)d_in[2];
    const float* V_b1    = (const float*)d_in[3];
    const float* V_w2    = (const float*)d_in[4];
    const float* V_b2    = (const float*)d_in[5];
    const float* Phi_w1  = (const float*)d_in[6];
    const float* Phi_b1  = (const float*)d_in[7];
    const float* Phi_w2  = (const float*)d_in[8];
    const float* Phi_b2  = (const float*)d_in[9];
    float* ws  = (float*)d_ws;
    float* out = (float*)d_out;

    main_kernel<<<PAIR_ROWS + EN_ROWS, NP, 0, stream>>>(
        data, t_snap, V_w1, V_b1, V_w2, V_b2, Phi_w1, Phi_b1, Phi_w2, Phi_b2, ws);

    reduce_kernel<<<1, 1024, 0, stream>>>(ws, out);
}